// Round 3
// baseline (213.321 us; speedup 1.0000x reference)
//
#include <hip/hip_runtime.h>
#include <math.h>

#define NN 20000
#define NE 640000
#define D  128
#define NSLICE 2500        // NN / 8 XCDs
#define NTILES 625         // NN / 32 rows per GEMM tile (exact)
#define SEG 128            // per-node bump-allocated segment (max degree; mean 32)
#define NCHUNK 640         // fill chunks
#define CHUNK 1000         // edges per chunk (640*1000 = NE)

typedef __attribute__((ext_vector_type(8))) short short8;
typedef __attribute__((ext_vector_type(4))) float floatx4;

static __device__ __forceinline__ unsigned short f2bf(float f) {
    union { float f; unsigned int u; } v; v.f = f;
    unsigned int u = v.u;
    u += 0x7fff + ((u >> 16) & 1);   // round-to-nearest-even
    return (unsigned short)(u >> 16);
}
static __device__ __forceinline__ unsigned int pack2bf(float a, float b) {
    return (unsigned int)f2bf(a) | ((unsigned int)f2bf(b) << 16);
}
static __device__ __forceinline__ float bf_lo(unsigned int u) {
    union { unsigned int i; float f; } v; v.i = u << 16; return v.f;
}
static __device__ __forceinline__ float bf_hi(unsigned int u) {
    union { unsigned int i; float f; } v; v.i = u & 0xffff0000u; return v.f;
}
static __device__ __forceinline__ float sigm(float x) { return 1.f / (1.f + __expf(-x)); }
static __device__ __forceinline__ float tanhx(float x) { return 1.f - 2.f / (__expf(2.f * x) + 1.f); }

static __device__ __forceinline__ void load_lds16(const void* g, void* l) {
    __builtin_amdgcn_global_load_lds(
        (const __attribute__((address_space(1))) unsigned int*)g,
        (__attribute__((address_space(3))) unsigned int*)l, 16, 0, 0);
}

// Fused prep + CSR fill (unchanged from R2 — control):
//  5120 blocks: VGPR=16, LDS=0 -> 8 blocks/CU resident = 32 waves/CU.
//  (a) blocks 0..2559: X/H bf16 pack. (a') 2560..2815: coalesced weight
//  transpose + bias fuse. (b) all blocks: slice-filtered bump fill with
//  vectorized unconditional edge loads; slice s = b&7 matches XCD id.
// Wsz layout (shorts): idx = ci*16384 + jg*4096 + col*8 + off, k = ci*32+jg*8+off.
__global__ void __launch_bounds__(256)
prep_fill_kernel(const int* __restrict__ src, const int* __restrict__ dst,
                 const float* __restrict__ ew, int* __restrict__ cnt,
                 unsigned int* __restrict__ s_p,
                 const float4* __restrict__ X4, const float4* __restrict__ H4,
                 unsigned int* __restrict__ XH32,
                 const float* __restrict__ Wx_l, const float* __restrict__ Wx_r,
                 const float* __restrict__ Wh_l, const float* __restrict__ Wh_r,
                 const float* __restrict__ bx, const float* __restrict__ bh,
                 const float* __restrict__ bg,
                 unsigned short* __restrict__ Wsz, float* __restrict__ bias) {
    int tid = threadIdx.x, b = blockIdx.x;       // 5120 blocks x 256 threads

    // (b) edge loads first so they are in flight under the (a) work
    int chunk = b >> 3, s = b & 7;
    int lo = s * NSLICE, hi = lo + NSLICE;
    int4 d4, sr4; float4 w4;
    bool fill = (tid < 250);
    if (fill) {
        int e0 = chunk * CHUNK + tid * 4;
        d4  = *(const int4*)(dst + e0);
        sr4 = *(const int4*)(src + e0);
        w4  = *(const float4*)(ew + e0);
    }

    if (b < 2560) {
        // (a) X/H pack, one element per thread
        int t = b * 256 + tid;
        if (t < NE) {
            float4 x = X4[t];
            float4 h = H4[t];
            int n = t >> 5, q = t & 31;
            unsigned int* row = XH32 + n * 128;
            row[2 * q]          = pack2bf(x.x, x.y);
            row[2 * q + 1]      = pack2bf(x.z, x.w);
            row[64 + 2 * q]     = pack2bf(h.x, h.y);
            row[64 + 2 * q + 1] = pack2bf(h.z, h.w);
        }
    } else if (b < 2816) {
        // (a') weight transpose, coalesced reads: t covers 2048 rows x 32 float4
        int t = (b - 2560) * 256 + tid;      // < 65536
        int row = t >> 5;                    // row = g*512 + k
        int g = row >> 9, k = row & 511;
        int o = (t & 31) * 4;
        const float* Wb; int kk;
        if (k < 128)      { Wb = Wx_l; kk = k; }
        else if (k < 256) { Wb = Wx_r; kk = k - 128; }
        else if (k < 384) { Wb = Wh_l; kk = k - 256; }
        else              { Wb = Wh_r; kk = k - 384; }
        float4 w = *(const float4*)(Wb + g * 16384 + kk * 128 + o);
        int ci = k >> 5, jg = (k >> 3) & 3, off = k & 7;
        unsigned short* wp = Wsz + ci * 16384 + jg * 4096 + (g * 128 + o) * 8 + off;
        wp[0]  = f2bf(w.x);
        wp[8]  = f2bf(w.y);
        wp[16] = f2bf(w.z);
        wp[24] = f2bf(w.w);
        if (k == 0) {
            int j0 = g * 128 + o;
#pragma unroll
            for (int i = 0; i < 4; ++i)
                bias[j0 + i] = bx[j0 + i] + bh[j0 + i] + bg[j0 + i];
        }
    }

    // (b) slice-filtered bump fill: 4 independent chains per thread
    if (fill) {
        int dv[4] = {d4.x, d4.y, d4.z, d4.w};
        int sv[4] = {sr4.x, sr4.y, sr4.z, sr4.w};
        float wv[4] = {w4.x, w4.y, w4.z, w4.w};
#pragma unroll
        for (int k = 0; k < 4; ++k) {
            int d = dv[k];
            if (d >= lo && d < hi) {
                int p = atomicAdd(&cnt[d], 1);
                if (p < SEG)
                    s_p[d * SEG + p] = (unsigned int)sv[k] | ((unsigned int)f2bf(wv[k]) << 16);
            }
        }
    }
}

// R3: 4-pass D-split aggregation for L2 residency.
// Old: wave owns a node, lane owns 8 B of the full 512 B row -> 328 MB of
// gather traffic against a 10 MB footprint; per-XCD L2 is 4 MB -> most
// gathers fall to L3. New: grid = 4 quarter-phases x 5000 blocks
// (q = bid/5000, slow-varying so concurrently-resident blocks share a
// phase). Per phase the gather footprint is NN x 128 B = 2.56 MB -> fits
// L2; same total bytes now served at ~34.5 TB/s.
// Wave layout: 1 node, 4 edges in flight via 16-lane groups (grp=lane>>4),
// lane owns 8 B of the 128 B quarter (fl=lane&15). 4x unroll keeps 16
// edge-gathers in flight per wave. Cross-group reduce: 8 shfl_xor.
// Segment lists re-read 4x (XCD-local L2, +7.5 MB total, negligible).
__global__ void __launch_bounds__(256)
aggregate_kernel(const unsigned short* __restrict__ XH,
                 const int* __restrict__ cnt,
                 const unsigned int* __restrict__ s_p,
                 unsigned short* __restrict__ AGG) {
    int wv = threadIdx.x >> 6, lane = threadIdx.x & 63;
    int grp = lane >> 4, fl = lane & 15;
    int bid = blockIdx.x;               // 0..19999
    int q = bid / 5000;                 // quarter phase 0..3
    int b2 = bid - q * 5000;
    int s = b2 & 7, j = b2 >> 3;        // XCD slice / tile
    int n = s * NSLICE + j * 4 + wv;
    int deg = cnt[n];
    int m = (deg < SEG) ? deg : SEG;
    const unsigned int* seg = s_p + (size_t)n * SEG;
    const unsigned short* base = XH + q * 64 + fl * 4;

    float a0 = 0.f, a1 = 0.f, a2 = 0.f, a3 = 0.f;
    int i = 0;
    for (; i + 16 <= m; i += 16) {
        unsigned int e[4];
        uint2 u[4];
#pragma unroll
        for (int k = 0; k < 4; ++k) e[k] = seg[i + k * 4 + grp];
#pragma unroll
        for (int k = 0; k < 4; ++k)
            u[k] = *(const uint2*)(base + (size_t)(e[k] & 0xffff) * 256);
#pragma unroll
        for (int k = 0; k < 4; ++k) {
            float w = __int_as_float(e[k] & 0xffff0000u);
            a0 += bf_lo(u[k].x) * w;
            a1 += bf_hi(u[k].x) * w;
            a2 += bf_lo(u[k].y) * w;
            a3 += bf_hi(u[k].y) * w;
        }
    }
    for (; i < m; i += 4) {
        int idx = i + grp;
        if (idx < m) {
            unsigned int e = seg[idx];
            float w = __int_as_float(e & 0xffff0000u);
            uint2 u = *(const uint2*)(base + (size_t)(e & 0xffff) * 256);
            a0 += bf_lo(u.x) * w;
            a1 += bf_hi(u.x) * w;
            a2 += bf_lo(u.y) * w;
            a3 += bf_hi(u.y) * w;
        }
    }

    // reduce the 4 edge-groups onto group 0 (same fl across groups)
#pragma unroll
    for (int mask = 16; mask < 64; mask <<= 1) {
        a0 += __shfl_xor(a0, mask, 64);
        a1 += __shfl_xor(a1, mask, 64);
        a2 += __shfl_xor(a2, mask, 64);
        a3 += __shfl_xor(a3, mask, 64);
    }

    if (grp == 0) {
        float inv = (deg > 0) ? 1.0f / (float)deg : 1.0f;
        uint2 r;
        r.x = pack2bf(a0 * inv, a1 * inv);
        r.y = pack2bf(a2 * inv, a3 * inv);
        *(uint2*)(AGG + (size_t)n * 256 + q * 64 + fl * 4) = r;
    }
}

// Fused GEMM + peephole-LSTM, N-split for occupancy (unchanged — control).
// 1250 blocks = 625 M-tiles x 2 column-halves; 2 x 16 KB LDS double buffer;
// 4 blocks/CU (16 waves/CU); in-register LSTM epilogue.
__global__ void __launch_bounds__(256)
gemm_lstm_kernel(const unsigned short* __restrict__ XH,
                 const unsigned short* __restrict__ AGG,
                 const unsigned short* __restrict__ Wsz,
                 const float* __restrict__ bias,
                 const float* __restrict__ wc,
                 const float* __restrict__ C,
                 float* __restrict__ out) {
    __shared__ __align__(16) short Bs[2][8192];  // [buf][jg*2048 + g*512 + c64*8 + off]

    int tid = threadIdx.x;
    int wv = tid >> 6, lane = tid & 63;
    int lm = lane & 15, lq = lane >> 4;
    int bid = blockIdx.x;
    int m0 = (bid >> 1) * 32;
    int hb = (bid & 1) * 512;           // half-offset in shorts: h*64 cols * 8

    floatx4 acc[2][4];
#pragma unroll
    for (int mt = 0; mt < 2; ++mt)
#pragma unroll
        for (int g = 0; g < 4; ++g) acc[mt][g] = (floatx4)(0.f);

    // stage chunk 0 into buf 0: wave wv stages (jg=wv, g=0..3), 1 KB each
#pragma unroll
    for (int g = 0; g < 4; ++g)
        load_lds16(Wsz + wv * 4096 + g * 1024 + hb + lane * 8,
                   &Bs[0][wv * 2048 + g * 512]);

    // A prefetch for kb=0 (segment aggX, offset 0 in AGG)
    short8 ca0, ca1;
    {
        const unsigned short* ar = AGG + (size_t)(m0 + lm) * 256 + lq * 8;
        ca0 = *(const short8*)ar;
        ca1 = *(const short8*)(ar + 16 * 256);
    }

    for (int it = 0; it < 16; ++it) {
        __syncthreads();   // drains staging (vmcnt0) + guards buffer reuse
        if (it < 15) {
            const unsigned short* wb = Wsz + (it + 1) * 16384 + wv * 4096 + hb;
            short* lb = &Bs[(it + 1) & 1][wv * 2048];
#pragma unroll
            for (int g = 0; g < 4; ++g)
                load_lds16(wb + g * 1024 + lane * 8, &lb[g * 512]);
        }
        // A prefetch for next iter
        short8 na0, na1;
        if (it < 15) {
            int kn = (it + 1) * 32;
            const unsigned short* ab = (kn & 128) ? XH : AGG;
            int aoff = (kn & 127) | ((kn & 256) >> 1);
            const unsigned short* arn = ab + (size_t)(m0 + lm) * 256 + aoff + lq * 8;
            na0 = *(const short8*)arn;
            na1 = *(const short8*)(arn + 16 * 256);
        }
        // B frags from LDS (conflict-free) + MFMA
        const short* bsc = Bs[it & 1];
#pragma unroll
        for (int g = 0; g < 4; ++g) {
            short8 bfr = *(const short8*)&bsc[(lq << 11) + (g << 9) + ((wv << 4) + lm) * 8];
            acc[0][g] = __builtin_amdgcn_mfma_f32_16x16x32_bf16(ca0, bfr, acc[0][g], 0, 0, 0);
            acc[1][g] = __builtin_amdgcn_mfma_f32_16x16x32_bf16(ca1, bfr, acc[1][g], 0, 0, 0);
        }
        ca0 = na0; ca1 = na1;
    }

    // epilogue: bias/peephole loads here (keeps K-loop register pressure low)
    int cg0 = (hb >> 3) + (wv << 4) + lm;   // hb/8 = h*64
    float bG[4], wP[3];
#pragma unroll
    for (int g = 0; g < 4; ++g) bG[g] = bias[(g << 7) + cg0];
#pragma unroll
    for (int j = 0; j < 3; ++j) wP[j] = wc[j * 128 + cg0];

#pragma unroll
    for (int mt = 0; mt < 2; ++mt)
#pragma unroll
        for (int r = 0; r < 4; ++r) {
            int row = m0 + mt * 16 + lq * 4 + r;   // 625*32 == NN exact, no guard
            float c = C[(size_t)row * D + cg0];
            float pi = acc[mt][0][r] + bG[0] + wP[0] * c;
            float pf = acc[mt][1][r] + bG[1] + wP[1] * c;
            float pt = acc[mt][2][r] + bG[2];
            float po = acc[mt][3][r] + bG[3];
            float I = sigm(pi);
            float F = sigm(pf);
            float T = tanhx(pt);
            float cn = F * c + I * T;
            float O = sigm(po + wP[2] * cn);
            out[(size_t)row * D + cg0] = O * tanhx(cn);
            out[(size_t)NN * D + (size_t)row * D + cg0] = cn;
        }
}

extern "C" void kernel_launch(void* const* d_in, const int* in_sizes, int n_in,
                              void* d_out, int out_size, void* d_ws, size_t ws_size,
                              hipStream_t stream) {
    const float* X  = (const float*)d_in[0];
    const int* ei   = (const int*)d_in[1];
    const float* ew = (const float*)d_in[2];
    const float* H  = (const float*)d_in[3];
    const float* C  = (const float*)d_in[4];
    const float* Wx_l = (const float*)d_in[5];
    const float* Wx_r = (const float*)d_in[6];
    const float* bx   = (const float*)d_in[7];
    const float* Wh_l = (const float*)d_in[8];
    const float* Wh_r = (const float*)d_in[9];
    const float* bh   = (const float*)d_in[10];
    const float* wc   = (const float*)d_in[11];
    const float* bg   = (const float*)d_in[12];
    float* out = (float*)d_out;

    const int* src = ei;
    const int* dst = ei + NE;

    // workspace layout (16B aligned), ~31.3 MB
    char* ws = (char*)d_ws;
    int* cnt = (int*)(ws + 0);                                //     80,000 B
    unsigned int* s_p = (unsigned int*)(ws + 80128);          // 10,240,000 B (20000*128*4)
    unsigned short* XH  = (unsigned short*)(ws + 10320128);   // 10,240,000 B
    unsigned short* AGG = (unsigned short*)(ws + 20560128);   // 10,240,000 B
    unsigned short* Wsz = (unsigned short*)(ws + 30800128);   //    524,288 B
    float* bias = (float*)(ws + 31324416);                    //      2,048 B

    hipMemsetAsync(cnt, 0, NN * sizeof(int), stream);
    prep_fill_kernel<<<5120, 256, 0, stream>>>(src, dst, ew, cnt, s_p,
                                               (const float4*)X, (const float4*)H,
                                               (unsigned int*)XH,
                                               Wx_l, Wx_r, Wh_l, Wh_r,
                                               bx, bh, bg, Wsz, bias);
    aggregate_kernel<<<20000, 256, 0, stream>>>(XH, cnt, s_p, AGG);
    gemm_lstm_kernel<<<NTILES * 2, 256, 0, stream>>>(XH, AGG, Wsz, bias, wc, C, out);
}

// Round 4
// 204.619 us; speedup vs baseline: 1.0425x; 1.0425x over previous
//
#include <hip/hip_runtime.h>
#include <math.h>

#define NN 20000
#define NE 640000
#define D  128
#define NSLICE 2500        // NN / 8 XCDs
#define NTILES 625         // NN / 32 rows per GEMM tile (exact)
#define SEG 128            // per-node bump-allocated segment (max degree; mean 32)
#define NCHUNK 640         // fill chunks
#define CHUNK 1000         // edges per chunk (640*1000 = NE)

typedef __attribute__((ext_vector_type(8))) short short8;
typedef __attribute__((ext_vector_type(4))) float floatx4;

static __device__ __forceinline__ unsigned short f2bf(float f) {
    union { float f; unsigned int u; } v; v.f = f;
    unsigned int u = v.u;
    u += 0x7fff + ((u >> 16) & 1);   // round-to-nearest-even
    return (unsigned short)(u >> 16);
}
static __device__ __forceinline__ unsigned int pack2bf(float a, float b) {
    return (unsigned int)f2bf(a) | ((unsigned int)f2bf(b) << 16);
}
static __device__ __forceinline__ float bf_lo(unsigned int u) {
    union { unsigned int i; float f; } v; v.i = u << 16; return v.f;
}
static __device__ __forceinline__ float bf_hi(unsigned int u) {
    union { unsigned int i; float f; } v; v.i = u & 0xffff0000u; return v.f;
}
static __device__ __forceinline__ float sigm(float x) { return 1.f / (1.f + __expf(-x)); }
static __device__ __forceinline__ float tanhx(float x) { return 1.f - 2.f / (__expf(2.f * x) + 1.f); }

static __device__ __forceinline__ void load_lds16(const void* g, void* l) {
    __builtin_amdgcn_global_load_lds(
        (const __attribute__((address_space(1))) unsigned int*)g,
        (__attribute__((address_space(3))) unsigned int*)l, 16, 0, 0);
}

// Fused prep + CSR fill (unchanged — control):
//  5120 blocks: VGPR=16, LDS=0 -> 8 blocks/CU resident = 32 waves/CU.
//  (a) blocks 0..2559: X/H bf16 pack. (a') 2560..2815: coalesced weight
//  transpose + bias fuse. (b) all blocks: slice-filtered bump fill with
//  vectorized unconditional edge loads; slice s = b&7 matches XCD id.
// Wsz layout (shorts): idx = ci*16384 + jg*4096 + col*8 + off, k = ci*32+jg*8+off.
__global__ void __launch_bounds__(256)
prep_fill_kernel(const int* __restrict__ src, const int* __restrict__ dst,
                 const float* __restrict__ ew, int* __restrict__ cnt,
                 unsigned int* __restrict__ s_p,
                 const float4* __restrict__ X4, const float4* __restrict__ H4,
                 unsigned int* __restrict__ XH32,
                 const float* __restrict__ Wx_l, const float* __restrict__ Wx_r,
                 const float* __restrict__ Wh_l, const float* __restrict__ Wh_r,
                 const float* __restrict__ bx, const float* __restrict__ bh,
                 const float* __restrict__ bg,
                 unsigned short* __restrict__ Wsz, float* __restrict__ bias) {
    int tid = threadIdx.x, b = blockIdx.x;       // 5120 blocks x 256 threads

    // (b) edge loads first so they are in flight under the (a) work
    int chunk = b >> 3, s = b & 7;
    int lo = s * NSLICE, hi = lo + NSLICE;
    int4 d4, sr4; float4 w4;
    bool fill = (tid < 250);
    if (fill) {
        int e0 = chunk * CHUNK + tid * 4;
        d4  = *(const int4*)(dst + e0);
        sr4 = *(const int4*)(src + e0);
        w4  = *(const float4*)(ew + e0);
    }

    if (b < 2560) {
        // (a) X/H pack, one element per thread
        int t = b * 256 + tid;
        if (t < NE) {
            float4 x = X4[t];
            float4 h = H4[t];
            int n = t >> 5, q = t & 31;
            unsigned int* row = XH32 + n * 128;
            row[2 * q]          = pack2bf(x.x, x.y);
            row[2 * q + 1]      = pack2bf(x.z, x.w);
            row[64 + 2 * q]     = pack2bf(h.x, h.y);
            row[64 + 2 * q + 1] = pack2bf(h.z, h.w);
        }
    } else if (b < 2816) {
        // (a') weight transpose, coalesced reads: t covers 2048 rows x 32 float4
        int t = (b - 2560) * 256 + tid;      // < 65536
        int row = t >> 5;                    // row = g*512 + k
        int g = row >> 9, k = row & 511;
        int o = (t & 31) * 4;
        const float* Wb; int kk;
        if (k < 128)      { Wb = Wx_l; kk = k; }
        else if (k < 256) { Wb = Wx_r; kk = k - 128; }
        else if (k < 384) { Wb = Wh_l; kk = k - 256; }
        else              { Wb = Wh_r; kk = k - 384; }
        float4 w = *(const float4*)(Wb + g * 16384 + kk * 128 + o);
        int ci = k >> 5, jg = (k >> 3) & 3, off = k & 7;
        unsigned short* wp = Wsz + ci * 16384 + jg * 4096 + (g * 128 + o) * 8 + off;
        wp[0]  = f2bf(w.x);
        wp[8]  = f2bf(w.y);
        wp[16] = f2bf(w.z);
        wp[24] = f2bf(w.w);
        if (k == 0) {
            int j0 = g * 128 + o;
#pragma unroll
            for (int i = 0; i < 4; ++i)
                bias[j0 + i] = bx[j0 + i] + bh[j0 + i] + bg[j0 + i];
        }
    }

    // (b) slice-filtered bump fill: 4 independent chains per thread
    if (fill) {
        int dv[4] = {d4.x, d4.y, d4.z, d4.w};
        int sv[4] = {sr4.x, sr4.y, sr4.z, sr4.w};
        float wv[4] = {w4.x, w4.y, w4.z, w4.w};
#pragma unroll
        for (int k = 0; k < 4; ++k) {
            int d = dv[k];
            if (d >= lo && d < hi) {
                int p = atomicAdd(&cnt[d], 1);
                if (p < SEG)
                    s_p[d * SEG + p] = (unsigned int)sv[k] | ((unsigned int)f2bf(wv[k]) << 16);
            }
        }
    }
}

// R4 aggregation: single-pass full-row gather (R2 structure) + WAVE-UNIFORM
// SCALARIZATION. Everything except the gathered row data is uniform across
// the wave: seg entries, weight, gather base. readfirstlane(n) lets the
// compiler's uniformity analysis place them in SGPRs:
//   - 16 seg reads -> one s_load_dwordx16 (SMEM, lgkmcnt: doesn't contend
//     with the gathers' vmcnt),
//   - per-edge address math + weight extract -> SALU,
//   - gather becomes saddr-form global_load_dwordx2 (voffset = lane*8),
//   - FMA reads w as its free SGPR operand.
// Per edge: 8 VALU + 1 VMEM (was ~13 VALU + 2 VMEM). 16 gathers in flight.
// Block->node mapping matches fill's XCD slicing (local-L2 seg reads).
__global__ void __launch_bounds__(256)
aggregate_kernel(const uint2* __restrict__ XH64,
                 const int* __restrict__ cnt,
                 const unsigned int* __restrict__ s_p,
                 uint2* __restrict__ AGG64) {
    int wv = threadIdx.x >> 6, lane = threadIdx.x & 63;
    int b = blockIdx.x;                 // 0..4999
    int s = b & 7, j = b >> 3;          // j: 0..624
    int n = __builtin_amdgcn_readfirstlane(s * NSLICE + j * 4 + wv);
    int deg = cnt[n];                   // uniform -> scalar load
    int m = (deg < SEG) ? deg : SEG;
    const unsigned int* seg = s_p + (size_t)n * SEG;
    float a0 = 0.f, a1 = 0.f, a2 = 0.f, a3 = 0.f;
    int i = 0;
    for (; i + 16 <= m; i += 16) {
        unsigned int e[16];
        uint2 u[16];
#pragma unroll
        for (int k = 0; k < 16; ++k) e[k] = seg[i + k];     // s_load_dwordx16
#pragma unroll
        for (int k = 0; k < 16; ++k)
            u[k] = XH64[(size_t)(e[k] & 0xffff) * 64 + lane];
#pragma unroll
        for (int k = 0; k < 16; ++k) {
            float w = __int_as_float(e[k] & 0xffff0000u);   // SALU
            a0 += bf_lo(u[k].x) * w;
            a1 += bf_hi(u[k].x) * w;
            a2 += bf_lo(u[k].y) * w;
            a3 += bf_hi(u[k].y) * w;
        }
    }
    for (; i + 4 <= m; i += 4) {
        unsigned int e[4];
        uint2 u[4];
#pragma unroll
        for (int k = 0; k < 4; ++k) e[k] = seg[i + k];
#pragma unroll
        for (int k = 0; k < 4; ++k)
            u[k] = XH64[(size_t)(e[k] & 0xffff) * 64 + lane];
#pragma unroll
        for (int k = 0; k < 4; ++k) {
            float w = __int_as_float(e[k] & 0xffff0000u);
            a0 += bf_lo(u[k].x) * w;
            a1 += bf_hi(u[k].x) * w;
            a2 += bf_lo(u[k].y) * w;
            a3 += bf_hi(u[k].y) * w;
        }
    }
    for (; i < m; ++i) {
        unsigned int e = seg[i];
        float w = __int_as_float(e & 0xffff0000u);
        uint2 u = XH64[(size_t)(e & 0xffff) * 64 + lane];
        a0 += bf_lo(u.x) * w;
        a1 += bf_hi(u.x) * w;
        a2 += bf_lo(u.y) * w;
        a3 += bf_hi(u.y) * w;
    }
    float inv = (deg > 0) ? 1.0f / (float)deg : 1.0f;
    uint2 r;
    r.x = pack2bf(a0 * inv, a1 * inv);
    r.y = pack2bf(a2 * inv, a3 * inv);
    AGG64[(size_t)n * 64 + lane] = r;
}

// Fused GEMM + peephole-LSTM, N-split for occupancy (unchanged — control).
// 1250 blocks = 625 M-tiles x 2 column-halves; 2 x 16 KB LDS double buffer;
// 4 blocks/CU (16 waves/CU); in-register LSTM epilogue.
__global__ void __launch_bounds__(256)
gemm_lstm_kernel(const unsigned short* __restrict__ XH,
                 const unsigned short* __restrict__ AGG,
                 const unsigned short* __restrict__ Wsz,
                 const float* __restrict__ bias,
                 const float* __restrict__ wc,
                 const float* __restrict__ C,
                 float* __restrict__ out) {
    __shared__ __align__(16) short Bs[2][8192];  // [buf][jg*2048 + g*512 + c64*8 + off]

    int tid = threadIdx.x;
    int wv = tid >> 6, lane = tid & 63;
    int lm = lane & 15, lq = lane >> 4;
    int bid = blockIdx.x;
    int m0 = (bid >> 1) * 32;
    int hb = (bid & 1) * 512;           // half-offset in shorts: h*64 cols * 8

    floatx4 acc[2][4];
#pragma unroll
    for (int mt = 0; mt < 2; ++mt)
#pragma unroll
        for (int g = 0; g < 4; ++g) acc[mt][g] = (floatx4)(0.f);

    // stage chunk 0 into buf 0: wave wv stages (jg=wv, g=0..3), 1 KB each
#pragma unroll
    for (int g = 0; g < 4; ++g)
        load_lds16(Wsz + wv * 4096 + g * 1024 + hb + lane * 8,
                   &Bs[0][wv * 2048 + g * 512]);

    // A prefetch for kb=0 (segment aggX, offset 0 in AGG)
    short8 ca0, ca1;
    {
        const unsigned short* ar = AGG + (size_t)(m0 + lm) * 256 + lq * 8;
        ca0 = *(const short8*)ar;
        ca1 = *(const short8*)(ar + 16 * 256);
    }

    for (int it = 0; it < 16; ++it) {
        __syncthreads();   // drains staging (vmcnt0) + guards buffer reuse
        if (it < 15) {
            const unsigned short* wb = Wsz + (it + 1) * 16384 + wv * 4096 + hb;
            short* lb = &Bs[(it + 1) & 1][wv * 2048];
#pragma unroll
            for (int g = 0; g < 4; ++g)
                load_lds16(wb + g * 1024 + lane * 8, &lb[g * 512]);
        }
        // A prefetch for next iter
        short8 na0, na1;
        if (it < 15) {
            int kn = (it + 1) * 32;
            const unsigned short* ab = (kn & 128) ? XH : AGG;
            int aoff = (kn & 127) | ((kn & 256) >> 1);
            const unsigned short* arn = ab + (size_t)(m0 + lm) * 256 + aoff + lq * 8;
            na0 = *(const short8*)arn;
            na1 = *(const short8*)(arn + 16 * 256);
        }
        // B frags from LDS (conflict-free) + MFMA
        const short* bsc = Bs[it & 1];
#pragma unroll
        for (int g = 0; g < 4; ++g) {
            short8 bfr = *(const short8*)&bsc[(lq << 11) + (g << 9) + ((wv << 4) + lm) * 8];
            acc[0][g] = __builtin_amdgcn_mfma_f32_16x16x32_bf16(ca0, bfr, acc[0][g], 0, 0, 0);
            acc[1][g] = __builtin_amdgcn_mfma_f32_16x16x32_bf16(ca1, bfr, acc[1][g], 0, 0, 0);
        }
        ca0 = na0; ca1 = na1;
    }

    // epilogue: bias/peephole loads here (keeps K-loop register pressure low)
    int cg0 = (hb >> 3) + (wv << 4) + lm;   // hb/8 = h*64
    float bG[4], wP[3];
#pragma unroll
    for (int g = 0; g < 4; ++g) bG[g] = bias[(g << 7) + cg0];
#pragma unroll
    for (int j = 0; j < 3; ++j) wP[j] = wc[j * 128 + cg0];

#pragma unroll
    for (int mt = 0; mt < 2; ++mt)
#pragma unroll
        for (int r = 0; r < 4; ++r) {
            int row = m0 + mt * 16 + lq * 4 + r;   // 625*32 == NN exact, no guard
            float c = C[(size_t)row * D + cg0];
            float pi = acc[mt][0][r] + bG[0] + wP[0] * c;
            float pf = acc[mt][1][r] + bG[1] + wP[1] * c;
            float pt = acc[mt][2][r] + bG[2];
            float po = acc[mt][3][r] + bG[3];
            float I = sigm(pi);
            float F = sigm(pf);
            float T = tanhx(pt);
            float cn = F * c + I * T;
            float O = sigm(po + wP[2] * cn);
            out[(size_t)row * D + cg0] = O * tanhx(cn);
            out[(size_t)NN * D + (size_t)row * D + cg0] = cn;
        }
}

extern "C" void kernel_launch(void* const* d_in, const int* in_sizes, int n_in,
                              void* d_out, int out_size, void* d_ws, size_t ws_size,
                              hipStream_t stream) {
    const float* X  = (const float*)d_in[0];
    const int* ei   = (const int*)d_in[1];
    const float* ew = (const float*)d_in[2];
    const float* H  = (const float*)d_in[3];
    const float* C  = (const float*)d_in[4];
    const float* Wx_l = (const float*)d_in[5];
    const float* Wx_r = (const float*)d_in[6];
    const float* bx   = (const float*)d_in[7];
    const float* Wh_l = (const float*)d_in[8];
    const float* Wh_r = (const float*)d_in[9];
    const float* bh   = (const float*)d_in[10];
    const float* wc   = (const float*)d_in[11];
    const float* bg   = (const float*)d_in[12];
    float* out = (float*)d_out;

    const int* src = ei;
    const int* dst = ei + NE;

    // workspace layout (16B aligned), ~31.3 MB
    char* ws = (char*)d_ws;
    int* cnt = (int*)(ws + 0);                                //     80,000 B
    unsigned int* s_p = (unsigned int*)(ws + 80128);          // 10,240,000 B (20000*128*4)
    unsigned short* XH  = (unsigned short*)(ws + 10320128);   // 10,240,000 B
    unsigned short* AGG = (unsigned short*)(ws + 20560128);   // 10,240,000 B
    unsigned short* Wsz = (unsigned short*)(ws + 30800128);   //    524,288 B
    float* bias = (float*)(ws + 31324416);                    //      2,048 B

    hipMemsetAsync(cnt, 0, NN * sizeof(int), stream);
    prep_fill_kernel<<<5120, 256, 0, stream>>>(src, dst, ew, cnt, s_p,
                                               (const float4*)X, (const float4*)H,
                                               (unsigned int*)XH,
                                               Wx_l, Wx_r, Wh_l, Wh_r,
                                               bx, bh, bg, Wsz, bias);
    aggregate_kernel<<<NN / 4, 256, 0, stream>>>((const uint2*)XH, cnt, s_p,
                                                 (uint2*)AGG);
    gemm_lstm_kernel<<<NTILES * 2, 256, 0, stream>>>(XH, AGG, Wsz, bias, wc, C, out);
}

// Round 6
// 200.650 us; speedup vs baseline: 1.0632x; 1.0198x over previous
//
#include <hip/hip_runtime.h>
#include <math.h>

#define NN 20000
#define NE 640000
#define D  128
#define NSLICE 2500        // NN / 8 XCDs
#define NTILES 625         // NN / 32 rows per GEMM tile (exact)
#define SUBSEG 40          // per-(node, src-quartile) sub-segment depth
#define SEGSTRIDE 160      // 4 * SUBSEG entries per node
#define NCHUNK 640         // fill chunks
#define CHUNK 1000         // edges per chunk (640*1000 = NE)

typedef __attribute__((ext_vector_type(8))) short short8;
typedef __attribute__((ext_vector_type(4))) float floatx4;

static __device__ __forceinline__ unsigned short f2bf(float f) {
    union { float f; unsigned int u; } v; v.f = f;
    unsigned int u = v.u;
    u += 0x7fff + ((u >> 16) & 1);   // round-to-nearest-even
    return (unsigned short)(u >> 16);
}
static __device__ __forceinline__ unsigned int pack2bf(float a, float b) {
    return (unsigned int)f2bf(a) | ((unsigned int)f2bf(b) << 16);
}
static __device__ __forceinline__ float bf_lo(unsigned int u) {
    union { unsigned int i; float f; } v; v.i = u << 16; return v.f;
}
static __device__ __forceinline__ float bf_hi(unsigned int u) {
    union { unsigned int i; float f; } v; v.i = u & 0xffff0000u; return v.f;
}
static __device__ __forceinline__ float sigm(float x) { return 1.f / (1.f + __expf(-x)); }
static __device__ __forceinline__ float tanhx(float x) { return 1.f - 2.f / (__expf(2.f * x) + 1.f); }

static __device__ __forceinline__ void load_lds16(const void* g, void* l) {
    __builtin_amdgcn_global_load_lds(
        (const __attribute__((address_space(1))) unsigned int*)g,
        (__attribute__((address_space(3))) unsigned int*)l, 16, 0, 0);
}

// Fused prep + CSR fill. R5 change: src-quartile-binned bump allocation.
// Each node owns 4 sub-segments of SUBSEG entries, binned by q = src/5000
// (sub-deg ~ Poisson(8); P(>40) ~ e^-34, i.e. never drops in practice).
// This lets the aggregate kernel walk the graph in 4 source-window passes
// (each window's rows = 2.56 MB -> fits per-XCD L2) with ZERO added
// per-edge cost — binning is paid here, once, with one extra int divide.
// Everything else (X/H pack, weight transpose, bias fuse, XCD slicing)
// unchanged from R4.
__global__ void __launch_bounds__(256)
prep_fill_kernel(const int* __restrict__ src, const int* __restrict__ dst,
                 const float* __restrict__ ew, int* __restrict__ cnt4,
                 unsigned int* __restrict__ s_p,
                 const float4* __restrict__ X4, const float4* __restrict__ H4,
                 unsigned int* __restrict__ XH32,
                 const float* __restrict__ Wx_l, const float* __restrict__ Wx_r,
                 const float* __restrict__ Wh_l, const float* __restrict__ Wh_r,
                 const float* __restrict__ bx, const float* __restrict__ bh,
                 const float* __restrict__ bg,
                 unsigned short* __restrict__ Wsz, float* __restrict__ bias) {
    int tid = threadIdx.x, b = blockIdx.x;       // 5120 blocks x 256 threads

    // (b) edge loads first so they are in flight under the (a) work
    int chunk = b >> 3, s = b & 7;
    int lo = s * NSLICE, hi = lo + NSLICE;
    int4 d4, sr4; float4 w4;
    bool fill = (tid < 250);
    if (fill) {
        int e0 = chunk * CHUNK + tid * 4;
        d4  = *(const int4*)(dst + e0);
        sr4 = *(const int4*)(src + e0);
        w4  = *(const float4*)(ew + e0);
    }

    if (b < 2560) {
        // (a) X/H pack, one element per thread
        int t = b * 256 + tid;
        if (t < NE) {
            float4 x = X4[t];
            float4 h = H4[t];
            int n = t >> 5, q = t & 31;
            unsigned int* row = XH32 + n * 128;
            row[2 * q]          = pack2bf(x.x, x.y);
            row[2 * q + 1]      = pack2bf(x.z, x.w);
            row[64 + 2 * q]     = pack2bf(h.x, h.y);
            row[64 + 2 * q + 1] = pack2bf(h.z, h.w);
        }
    } else if (b < 2816) {
        // (a') weight transpose, coalesced reads: t covers 2048 rows x 32 float4
        int t = (b - 2560) * 256 + tid;      // < 65536
        int row = t >> 5;                    // row = g*512 + k
        int g = row >> 9, k = row & 511;
        int o = (t & 31) * 4;
        const float* Wb; int kk;
        if (k < 128)      { Wb = Wx_l; kk = k; }
        else if (k < 256) { Wb = Wx_r; kk = k - 128; }
        else if (k < 384) { Wb = Wh_l; kk = k - 256; }
        else              { Wb = Wh_r; kk = k - 384; }
        float4 w = *(const float4*)(Wb + g * 16384 + kk * 128 + o);
        int ci = k >> 5, jg = (k >> 3) & 3, off = k & 7;
        unsigned short* wp = Wsz + ci * 16384 + jg * 4096 + (g * 128 + o) * 8 + off;
        wp[0]  = f2bf(w.x);
        wp[8]  = f2bf(w.y);
        wp[16] = f2bf(w.z);
        wp[24] = f2bf(w.w);
        if (k == 0) {
            int j0 = g * 128 + o;
#pragma unroll
            for (int i = 0; i < 4; ++i)
                bias[j0 + i] = bx[j0 + i] + bh[j0 + i] + bg[j0 + i];
        }
    }

    // (b) slice-filtered, src-quartile-binned bump fill
    if (fill) {
        int dv[4] = {d4.x, d4.y, d4.z, d4.w};
        int sv[4] = {sr4.x, sr4.y, sr4.z, sr4.w};
        float wv[4] = {w4.x, w4.y, w4.z, w4.w};
#pragma unroll
        for (int k = 0; k < 4; ++k) {
            int d = dv[k];
            if (d >= lo && d < hi) {
                int q = (int)((unsigned)sv[k] / 5000u);   // src window 0..3
                int p = atomicAdd(&cnt4[d * 4 + q], 1);
                if (p < SUBSEG)
                    s_p[d * SEGSTRIDE + q * SUBSEG + p] =
                        (unsigned int)sv[k] | ((unsigned int)f2bf(wv[k]) << 16);
            }
        }
    }
}

// R5 aggregation: 4 source-window passes, in-register partials.
// Pass p touches only XH rows in [p*5000, (p+1)*5000): a 2.56 MB window
// that fits every XCD's 4 MB L2. All resident waves start pass 0 together
// (single dispatch, per-wave pass loop), so concurrently-live windows are
// at most two adjacent ones -> the 328 MB of row-gathers are served mostly
// at L2 speed instead of the ~9 TB/s L3 wall measured in R4.
// Per-edge cost is identical to R4 (scalarized seg reads / weight / address;
// full-row 8 B/lane gather; no filtering, no cross-lane reduce) because the
// binning was done at fill time. Accumulators persist across passes in
// registers; divisor = sum of the 4 true sub-counts.
__global__ void __launch_bounds__(256)
aggregate_kernel(const uint2* __restrict__ XH64,
                 const int* __restrict__ cnt4,
                 const unsigned int* __restrict__ s_p,
                 uint2* __restrict__ AGG64) {
    int wv = threadIdx.x >> 6, lane = threadIdx.x & 63;
    int b = blockIdx.x;                 // 0..4999
    int s = b & 7, j = b >> 3;          // j: 0..624
    int n = __builtin_amdgcn_readfirstlane(s * NSLICE + j * 4 + wv);
    int c0 = cnt4[n * 4 + 0];           // uniform -> scalar loads
    int c1 = cnt4[n * 4 + 1];
    int c2 = cnt4[n * 4 + 2];
    int c3 = cnt4[n * 4 + 3];
    int deg = c0 + c1 + c2 + c3;
    const unsigned int* segbase = s_p + (size_t)n * SEGSTRIDE;
    float a0 = 0.f, a1 = 0.f, a2 = 0.f, a3 = 0.f;

#pragma unroll
    for (int p = 0; p < 4; ++p) {
        int c = (p == 0) ? c0 : (p == 1) ? c1 : (p == 2) ? c2 : c3;
        int m = (c < SUBSEG) ? c : SUBSEG;
        const unsigned int* seg = segbase + p * SUBSEG;
        int i = 0;
        for (; i + 8 <= m; i += 8) {
            unsigned int e[8];
            uint2 u[8];
#pragma unroll
            for (int k = 0; k < 8; ++k) e[k] = seg[i + k];   // scalar
#pragma unroll
            for (int k = 0; k < 8; ++k)
                u[k] = XH64[(size_t)(e[k] & 0xffff) * 64 + lane];
#pragma unroll
            for (int k = 0; k < 8; ++k) {
                float w = __int_as_float(e[k] & 0xffff0000u);
                a0 += bf_lo(u[k].x) * w;
                a1 += bf_hi(u[k].x) * w;
                a2 += bf_lo(u[k].y) * w;
                a3 += bf_hi(u[k].y) * w;
            }
        }
        for (; i + 4 <= m; i += 4) {
            unsigned int e[4];
            uint2 u[4];
#pragma unroll
            for (int k = 0; k < 4; ++k) e[k] = seg[i + k];
#pragma unroll
            for (int k = 0; k < 4; ++k)
                u[k] = XH64[(size_t)(e[k] & 0xffff) * 64 + lane];
#pragma unroll
            for (int k = 0; k < 4; ++k) {
                float w = __int_as_float(e[k] & 0xffff0000u);
                a0 += bf_lo(u[k].x) * w;
                a1 += bf_hi(u[k].x) * w;
                a2 += bf_lo(u[k].y) * w;
                a3 += bf_hi(u[k].y) * w;
            }
        }
        for (; i < m; ++i) {
            unsigned int e = seg[i];
            float w = __int_as_float(e & 0xffff0000u);
            uint2 u = XH64[(size_t)(e & 0xffff) * 64 + lane];
            a0 += bf_lo(u.x) * w;
            a1 += bf_hi(u.x) * w;
            a2 += bf_lo(u.y) * w;
            a3 += bf_hi(u.y) * w;
        }
    }

    float inv = (deg > 0) ? 1.0f / (float)deg : 1.0f;
    uint2 r;
    r.x = pack2bf(a0 * inv, a1 * inv);
    r.y = pack2bf(a2 * inv, a3 * inv);
    AGG64[(size_t)n * 64 + lane] = r;
}

// Fused GEMM + peephole-LSTM, N-split for occupancy (unchanged — control).
// 1250 blocks = 625 M-tiles x 2 column-halves; 2 x 16 KB LDS double buffer;
// 4 blocks/CU (16 waves/CU); in-register LSTM epilogue.
__global__ void __launch_bounds__(256)
gemm_lstm_kernel(const unsigned short* __restrict__ XH,
                 const unsigned short* __restrict__ AGG,
                 const unsigned short* __restrict__ Wsz,
                 const float* __restrict__ bias,
                 const float* __restrict__ wc,
                 const float* __restrict__ C,
                 float* __restrict__ out) {
    __shared__ __align__(16) short Bs[2][8192];  // [buf][jg*2048 + g*512 + c64*8 + off]

    int tid = threadIdx.x;
    int wv = tid >> 6, lane = tid & 63;
    int lm = lane & 15, lq = lane >> 4;
    int bid = blockIdx.x;
    int m0 = (bid >> 1) * 32;
    int hb = (bid & 1) * 512;           // half-offset in shorts: h*64 cols * 8

    floatx4 acc[2][4];
#pragma unroll
    for (int mt = 0; mt < 2; ++mt)
#pragma unroll
        for (int g = 0; g < 4; ++g) acc[mt][g] = (floatx4)(0.f);

    // stage chunk 0 into buf 0: wave wv stages (jg=wv, g=0..3), 1 KB each
#pragma unroll
    for (int g = 0; g < 4; ++g)
        load_lds16(Wsz + wv * 4096 + g * 1024 + hb + lane * 8,
                   &Bs[0][wv * 2048 + g * 512]);

    // A prefetch for kb=0 (segment aggX, offset 0 in AGG)
    short8 ca0, ca1;
    {
        const unsigned short* ar = AGG + (size_t)(m0 + lm) * 256 + lq * 8;
        ca0 = *(const short8*)ar;
        ca1 = *(const short8*)(ar + 16 * 256);
    }

    for (int it = 0; it < 16; ++it) {
        __syncthreads();   // drains staging (vmcnt0) + guards buffer reuse
        if (it < 15) {
            const unsigned short* wb = Wsz + (it + 1) * 16384 + wv * 4096 + hb;
            short* lb = &Bs[(it + 1) & 1][wv * 2048];
#pragma unroll
            for (int g = 0; g < 4; ++g)
                load_lds16(wb + g * 1024 + lane * 8, &lb[g * 512]);
        }
        // A prefetch for next iter
        short8 na0, na1;
        if (it < 15) {
            int kn = (it + 1) * 32;
            const unsigned short* ab = (kn & 128) ? XH : AGG;
            int aoff = (kn & 127) | ((kn & 256) >> 1);
            const unsigned short* arn = ab + (size_t)(m0 + lm) * 256 + aoff + lq * 8;
            na0 = *(const short8*)arn;
            na1 = *(const short8*)(arn + 16 * 256);
        }
        // B frags from LDS (conflict-free) + MFMA
        const short* bsc = Bs[it & 1];
#pragma unroll
        for (int g = 0; g < 4; ++g) {
            short8 bfr = *(const short8*)&bsc[(lq << 11) + (g << 9) + ((wv << 4) + lm) * 8];
            acc[0][g] = __builtin_amdgcn_mfma_f32_16x16x32_bf16(ca0, bfr, acc[0][g], 0, 0, 0);
            acc[1][g] = __builtin_amdgcn_mfma_f32_16x16x32_bf16(ca1, bfr, acc[1][g], 0, 0, 0);
        }
        ca0 = na0; ca1 = na1;
    }

    // epilogue: bias/peephole loads here (keeps K-loop register pressure low)
    int cg0 = (hb >> 3) + (wv << 4) + lm;   // hb/8 = h*64
    float bG[4], wP[3];
#pragma unroll
    for (int g = 0; g < 4; ++g) bG[g] = bias[(g << 7) + cg0];
#pragma unroll
    for (int j = 0; j < 3; ++j) wP[j] = wc[j * 128 + cg0];

#pragma unroll
    for (int mt = 0; mt < 2; ++mt)
#pragma unroll
        for (int r = 0; r < 4; ++r) {
            int row = m0 + mt * 16 + lq * 4 + r;   // 625*32 == NN exact, no guard
            float c = C[(size_t)row * D + cg0];
            float pi = acc[mt][0][r] + bG[0] + wP[0] * c;
            float pf = acc[mt][1][r] + bG[1] + wP[1] * c;
            float pt = acc[mt][2][r] + bG[2];
            float po = acc[mt][3][r] + bG[3];
            float I = sigm(pi);
            float F = sigm(pf);
            float T = tanhx(pt);
            float cn = F * c + I * T;
            float O = sigm(po + wP[2] * cn);
            out[(size_t)row * D + cg0] = O * tanhx(cn);
            out[(size_t)NN * D + (size_t)row * D + cg0] = cn;
        }
}

extern "C" void kernel_launch(void* const* d_in, const int* in_sizes, int n_in,
                              void* d_out, int out_size, void* d_ws, size_t ws_size,
                              hipStream_t stream) {
    const float* X  = (const float*)d_in[0];
    const int* ei   = (const int*)d_in[1];
    const float* ew = (const float*)d_in[2];
    const float* H  = (const float*)d_in[3];
    const float* C  = (const float*)d_in[4];
    const float* Wx_l = (const float*)d_in[5];
    const float* Wx_r = (const float*)d_in[6];
    const float* bx   = (const float*)d_in[7];
    const float* Wh_l = (const float*)d_in[8];
    const float* Wh_r = (const float*)d_in[9];
    const float* bh   = (const float*)d_in[10];
    const float* wc   = (const float*)d_in[11];
    const float* bg   = (const float*)d_in[12];
    float* out = (float*)d_out;

    const int* src = ei;
    const int* dst = ei + NE;

    // workspace layout (16B aligned), ~34.1 MB (workspace is >=256 MB)
    char* ws = (char*)d_ws;
    int* cnt4 = (int*)(ws + 0);                               //    320,000 B (20000*4 ints)
    unsigned int* s_p = (unsigned int*)(ws + 320128);         // 12,800,000 B (20000*160*4)
    unsigned short* XH  = (unsigned short*)(ws + 13120128);   // 10,240,000 B
    unsigned short* AGG = (unsigned short*)(ws + 23360128);   // 10,240,000 B
    unsigned short* Wsz = (unsigned short*)(ws + 33600128);   //    524,288 B
    float* bias = (float*)(ws + 34124416);                    //      2,048 B

    hipMemsetAsync(cnt4, 0, NN * 4 * sizeof(int), stream);
    prep_fill_kernel<<<5120, 256, 0, stream>>>(src, dst, ew, cnt4, s_p,
                                               (const float4*)X, (const float4*)H,
                                               (unsigned int*)XH,
                                               Wx_l, Wx_r, Wh_l, Wh_r,
                                               bx, bh, bg, Wsz, bias);
    aggregate_kernel<<<NN / 4, 256, 0, stream>>>((const uint2*)XH, cnt4, s_p,
                                                 (uint2*)AGG);
    gemm_lstm_kernel<<<NTILES * 2, 256, 0, stream>>>(XH, AGG, Wsz, bias, wc, C, out);
}

// Round 7
// 197.155 us; speedup vs baseline: 1.0820x; 1.0177x over previous
//
#include <hip/hip_runtime.h>
#include <math.h>

#define NN 20000
#define NE 640000
#define D  128
#define NSLICE 2500        // NN / 8 XCDs
#define NTILES 625         // NN / 32 rows per GEMM tile (exact)
#define SUBSEG 40          // per-(node, src-quartile) sub-segment depth
#define SEGSTRIDE 160      // 4 * SUBSEG entries per node
#define NCHUNK 640         // fill chunks
#define CHUNK 1000         // edges per chunk (640*1000 = NE)

typedef __attribute__((ext_vector_type(8))) short short8;
typedef __attribute__((ext_vector_type(4))) float floatx4;

static __device__ __forceinline__ unsigned short f2bf(float f) {
    union { float f; unsigned int u; } v; v.f = f;
    unsigned int u = v.u;
    u += 0x7fff + ((u >> 16) & 1);   // round-to-nearest-even
    return (unsigned short)(u >> 16);
}
static __device__ __forceinline__ unsigned int pack2bf(float a, float b) {
    return (unsigned int)f2bf(a) | ((unsigned int)f2bf(b) << 16);
}
static __device__ __forceinline__ float bf_lo(unsigned int u) {
    union { unsigned int i; float f; } v; v.i = u << 16; return v.f;
}
static __device__ __forceinline__ float bf_hi(unsigned int u) {
    union { unsigned int i; float f; } v; v.i = u & 0xffff0000u; return v.f;
}
static __device__ __forceinline__ float sigm(float x) { return 1.f / (1.f + __expf(-x)); }
static __device__ __forceinline__ float tanhx(float x) { return 1.f - 2.f / (__expf(2.f * x) + 1.f); }

// Fused prep + CSR fill (unchanged — control). Src-quartile-binned bump
// allocation: each node owns 4 sub-segments of SUBSEG entries, binned by
// q = src/5000 (sub-deg ~ Poisson(8); P(>40) ~ e^-34). Lets aggregate walk
// the graph in 4 L2-resident source-window passes with zero added per-edge
// cost. X/H bf16 pack, coalesced weight transpose, bias fuse, XCD slicing.
// Wsz layout (shorts): idx = ci*16384 + jg*4096 + col*8 + off, k = ci*32+jg*8+off.
__global__ void __launch_bounds__(256)
prep_fill_kernel(const int* __restrict__ src, const int* __restrict__ dst,
                 const float* __restrict__ ew, int* __restrict__ cnt4,
                 unsigned int* __restrict__ s_p,
                 const float4* __restrict__ X4, const float4* __restrict__ H4,
                 unsigned int* __restrict__ XH32,
                 const float* __restrict__ Wx_l, const float* __restrict__ Wx_r,
                 const float* __restrict__ Wh_l, const float* __restrict__ Wh_r,
                 const float* __restrict__ bx, const float* __restrict__ bh,
                 const float* __restrict__ bg,
                 unsigned short* __restrict__ Wsz, float* __restrict__ bias) {
    int tid = threadIdx.x, b = blockIdx.x;       // 5120 blocks x 256 threads

    // (b) edge loads first so they are in flight under the (a) work
    int chunk = b >> 3, s = b & 7;
    int lo = s * NSLICE, hi = lo + NSLICE;
    int4 d4, sr4; float4 w4;
    bool fill = (tid < 250);
    if (fill) {
        int e0 = chunk * CHUNK + tid * 4;
        d4  = *(const int4*)(dst + e0);
        sr4 = *(const int4*)(src + e0);
        w4  = *(const float4*)(ew + e0);
    }

    if (b < 2560) {
        // (a) X/H pack, one element per thread
        int t = b * 256 + tid;
        if (t < NE) {
            float4 x = X4[t];
            float4 h = H4[t];
            int n = t >> 5, q = t & 31;
            unsigned int* row = XH32 + n * 128;
            row[2 * q]          = pack2bf(x.x, x.y);
            row[2 * q + 1]      = pack2bf(x.z, x.w);
            row[64 + 2 * q]     = pack2bf(h.x, h.y);
            row[64 + 2 * q + 1] = pack2bf(h.z, h.w);
        }
    } else if (b < 2816) {
        // (a') weight transpose, coalesced reads: t covers 2048 rows x 32 float4
        int t = (b - 2560) * 256 + tid;      // < 65536
        int row = t >> 5;                    // row = g*512 + k
        int g = row >> 9, k = row & 511;
        int o = (t & 31) * 4;
        const float* Wb; int kk;
        if (k < 128)      { Wb = Wx_l; kk = k; }
        else if (k < 256) { Wb = Wx_r; kk = k - 128; }
        else if (k < 384) { Wb = Wh_l; kk = k - 256; }
        else              { Wb = Wh_r; kk = k - 384; }
        float4 w = *(const float4*)(Wb + g * 16384 + kk * 128 + o);
        int ci = k >> 5, jg = (k >> 3) & 3, off = k & 7;
        unsigned short* wp = Wsz + ci * 16384 + jg * 4096 + (g * 128 + o) * 8 + off;
        wp[0]  = f2bf(w.x);
        wp[8]  = f2bf(w.y);
        wp[16] = f2bf(w.z);
        wp[24] = f2bf(w.w);
        if (k == 0) {
            int j0 = g * 128 + o;
#pragma unroll
            for (int i = 0; i < 4; ++i)
                bias[j0 + i] = bx[j0 + i] + bh[j0 + i] + bg[j0 + i];
        }
    }

    // (b) slice-filtered, src-quartile-binned bump fill
    if (fill) {
        int dv[4] = {d4.x, d4.y, d4.z, d4.w};
        int sv[4] = {sr4.x, sr4.y, sr4.z, sr4.w};
        float wv[4] = {w4.x, w4.y, w4.z, w4.w};
#pragma unroll
        for (int k = 0; k < 4; ++k) {
            int d = dv[k];
            if (d >= lo && d < hi) {
                int q = (int)((unsigned)sv[k] / 5000u);   // src window 0..3
                int p = atomicAdd(&cnt4[d * 4 + q], 1);
                if (p < SUBSEG)
                    s_p[d * SEGSTRIDE + q * SUBSEG + p] =
                        (unsigned int)sv[k] | ((unsigned int)f2bf(wv[k]) << 16);
            }
        }
    }
}

// Aggregation (unchanged — control): 4 source-window passes (2.56 MB window
// fits per-XCD L2), in-register partials, scalarized seg reads / weights /
// addresses via readfirstlane(n), full-row 8 B/lane gathers.
__global__ void __launch_bounds__(256)
aggregate_kernel(const uint2* __restrict__ XH64,
                 const int* __restrict__ cnt4,
                 const unsigned int* __restrict__ s_p,
                 uint2* __restrict__ AGG64) {
    int wv = threadIdx.x >> 6, lane = threadIdx.x & 63;
    int b = blockIdx.x;                 // 0..4999
    int s = b & 7, j = b >> 3;          // j: 0..624
    int n = __builtin_amdgcn_readfirstlane(s * NSLICE + j * 4 + wv);
    int c0 = cnt4[n * 4 + 0];           // uniform -> scalar loads
    int c1 = cnt4[n * 4 + 1];
    int c2 = cnt4[n * 4 + 2];
    int c3 = cnt4[n * 4 + 3];
    int deg = c0 + c1 + c2 + c3;
    const unsigned int* segbase = s_p + (size_t)n * SEGSTRIDE;
    float a0 = 0.f, a1 = 0.f, a2 = 0.f, a3 = 0.f;

#pragma unroll
    for (int p = 0; p < 4; ++p) {
        int c = (p == 0) ? c0 : (p == 1) ? c1 : (p == 2) ? c2 : c3;
        int m = (c < SUBSEG) ? c : SUBSEG;
        const unsigned int* seg = segbase + p * SUBSEG;
        int i = 0;
        for (; i + 8 <= m; i += 8) {
            unsigned int e[8];
            uint2 u[8];
#pragma unroll
            for (int k = 0; k < 8; ++k) e[k] = seg[i + k];   // scalar
#pragma unroll
            for (int k = 0; k < 8; ++k)
                u[k] = XH64[(size_t)(e[k] & 0xffff) * 64 + lane];
#pragma unroll
            for (int k = 0; k < 8; ++k) {
                float w = __int_as_float(e[k] & 0xffff0000u);
                a0 += bf_lo(u[k].x) * w;
                a1 += bf_hi(u[k].x) * w;
                a2 += bf_lo(u[k].y) * w;
                a3 += bf_hi(u[k].y) * w;
            }
        }
        for (; i + 4 <= m; i += 4) {
            unsigned int e[4];
            uint2 u[4];
#pragma unroll
            for (int k = 0; k < 4; ++k) e[k] = seg[i + k];
#pragma unroll
            for (int k = 0; k < 4; ++k)
                u[k] = XH64[(size_t)(e[k] & 0xffff) * 64 + lane];
#pragma unroll
            for (int k = 0; k < 4; ++k) {
                float w = __int_as_float(e[k] & 0xffff0000u);
                a0 += bf_lo(u[k].x) * w;
                a1 += bf_hi(u[k].x) * w;
                a2 += bf_lo(u[k].y) * w;
                a3 += bf_hi(u[k].y) * w;
            }
        }
        for (; i < m; ++i) {
            unsigned int e = seg[i];
            float w = __int_as_float(e & 0xffff0000u);
            uint2 u = XH64[(size_t)(e & 0xffff) * 64 + lane];
            a0 += bf_lo(u.x) * w;
            a1 += bf_hi(u.x) * w;
            a2 += bf_lo(u.y) * w;
            a3 += bf_hi(u.y) * w;
        }
    }

    float inv = (deg > 0) ? 1.0f / (float)deg : 1.0f;
    uint2 r;
    r.x = pack2bf(a0 * inv, a1 * inv);
    r.y = pack2bf(a2 * inv, a3 * inv);
    AGG64[(size_t)n * 64 + lane] = r;
}

// R7 GEMM + peephole-LSTM: LDS ELIMINATED, barrier-free K-loop.
// R6 audit showed the staged 16 KB/iter was consumed exactly once (4 waves
// x 4 KB disjoint ds_reads) — zero intra-block reuse. The only B reuse is
// ACROSS blocks, already served by L2 (Wsz = 512 KB, XCD-resident). So the
// stage -> vmcnt(0) -> barrier x2 per iter was pure serialization (the
// measured 26% occupancy / 8% MfmaUtil latency wall).
// Now each thread vector-loads its four B fragments straight from Wsz
// (16-lane groups read 256 B contiguous -> coalesced L2 hits) with
// next-iter prefetch registers for both A and B: 6 independent VMEM in
// flight per wave per iter, no __syncthreads, LDS_Block_Size = 0.
// 1250 blocks = 625 M-tiles x 2 column-halves; wave wv owns cols
// [h*64 + wv*16, +16) of all 4 gates; in-register LSTM epilogue unchanged.
__global__ void __launch_bounds__(256)
gemm_lstm_kernel(const unsigned short* __restrict__ XH,
                 const unsigned short* __restrict__ AGG,
                 const unsigned short* __restrict__ Wsz,
                 const float* __restrict__ bias,
                 const float* __restrict__ wc,
                 const float* __restrict__ C,
                 float* __restrict__ out) {
    int tid = threadIdx.x;
    int wv = tid >> 6, lane = tid & 63;
    int lm = lane & 15, lq = lane >> 4;
    int bid = blockIdx.x;
    int m0 = (bid >> 1) * 32;
    int hb = (bid & 1) * 512;           // half-offset in shorts: h*64 cols * 8

    floatx4 acc[2][4];
#pragma unroll
    for (int mt = 0; mt < 2; ++mt)
#pragma unroll
        for (int g = 0; g < 4; ++g) acc[mt][g] = (floatx4)(0.f);

    // per-thread B source base (shorts); iter it, gate g lives at
    // + it*16384 + g*1024. 16-B aligned; 16-lane groups contiguous 256 B.
    const unsigned short* wbase = Wsz + hb + lq * 4096 + ((wv << 4) + lm) * 8;

    // prefetch it=0: A (segment aggX, offset 0 in AGG) + B (4 gates)
    short8 ca0, ca1, cb0, cb1, cb2, cb3;
    {
        const unsigned short* ar = AGG + (size_t)(m0 + lm) * 256 + lq * 8;
        ca0 = *(const short8*)ar;
        ca1 = *(const short8*)(ar + 16 * 256);
    }
    cb0 = *(const short8*)(wbase);
    cb1 = *(const short8*)(wbase + 1024);
    cb2 = *(const short8*)(wbase + 2048);
    cb3 = *(const short8*)(wbase + 3072);

    for (int it = 0; it < 16; ++it) {
        short8 na0, na1, nb0, nb1, nb2, nb3;
        if (it < 15) {
            int kn = (it + 1) * 32;
            const unsigned short* ab = (kn & 128) ? XH : AGG;
            int aoff = (kn & 127) | ((kn & 256) >> 1);
            const unsigned short* arn = ab + (size_t)(m0 + lm) * 256 + aoff + lq * 8;
            na0 = *(const short8*)arn;
            na1 = *(const short8*)(arn + 16 * 256);
            const unsigned short* wb = wbase + (it + 1) * 16384;
            nb0 = *(const short8*)(wb);
            nb1 = *(const short8*)(wb + 1024);
            nb2 = *(const short8*)(wb + 2048);
            nb3 = *(const short8*)(wb + 3072);
        }
        acc[0][0] = __builtin_amdgcn_mfma_f32_16x16x32_bf16(ca0, cb0, acc[0][0], 0, 0, 0);
        acc[1][0] = __builtin_amdgcn_mfma_f32_16x16x32_bf16(ca1, cb0, acc[1][0], 0, 0, 0);
        acc[0][1] = __builtin_amdgcn_mfma_f32_16x16x32_bf16(ca0, cb1, acc[0][1], 0, 0, 0);
        acc[1][1] = __builtin_amdgcn_mfma_f32_16x16x32_bf16(ca1, cb1, acc[1][1], 0, 0, 0);
        acc[0][2] = __builtin_amdgcn_mfma_f32_16x16x32_bf16(ca0, cb2, acc[0][2], 0, 0, 0);
        acc[1][2] = __builtin_amdgcn_mfma_f32_16x16x32_bf16(ca1, cb2, acc[1][2], 0, 0, 0);
        acc[0][3] = __builtin_amdgcn_mfma_f32_16x16x32_bf16(ca0, cb3, acc[0][3], 0, 0, 0);
        acc[1][3] = __builtin_amdgcn_mfma_f32_16x16x32_bf16(ca1, cb3, acc[1][3], 0, 0, 0);
        ca0 = na0; ca1 = na1;
        cb0 = nb0; cb1 = nb1; cb2 = nb2; cb3 = nb3;
    }

    // epilogue: bias/peephole loads here (keeps K-loop register pressure low)
    int cg0 = (hb >> 3) + (wv << 4) + lm;   // hb/8 = h*64
    float bG[4], wP[3];
#pragma unroll
    for (int g = 0; g < 4; ++g) bG[g] = bias[(g << 7) + cg0];
#pragma unroll
    for (int j = 0; j < 3; ++j) wP[j] = wc[j * 128 + cg0];

#pragma unroll
    for (int mt = 0; mt < 2; ++mt)
#pragma unroll
        for (int r = 0; r < 4; ++r) {
            int row = m0 + mt * 16 + lq * 4 + r;   // 625*32 == NN exact, no guard
            float c = C[(size_t)row * D + cg0];
            float pi = acc[mt][0][r] + bG[0] + wP[0] * c;
            float pf = acc[mt][1][r] + bG[1] + wP[1] * c;
            float pt = acc[mt][2][r] + bG[2];
            float po = acc[mt][3][r] + bG[3];
            float I = sigm(pi);
            float F = sigm(pf);
            float T = tanhx(pt);
            float cn = F * c + I * T;
            float O = sigm(po + wP[2] * cn);
            out[(size_t)row * D + cg0] = O * tanhx(cn);
            out[(size_t)NN * D + (size_t)row * D + cg0] = cn;
        }
}

extern "C" void kernel_launch(void* const* d_in, const int* in_sizes, int n_in,
                              void* d_out, int out_size, void* d_ws, size_t ws_size,
                              hipStream_t stream) {
    const float* X  = (const float*)d_in[0];
    const int* ei   = (const int*)d_in[1];
    const float* ew = (const float*)d_in[2];
    const float* H  = (const float*)d_in[3];
    const float* C  = (const float*)d_in[4];
    const float* Wx_l = (const float*)d_in[5];
    const float* Wx_r = (const float*)d_in[6];
    const float* bx   = (const float*)d_in[7];
    const float* Wh_l = (const float*)d_in[8];
    const float* Wh_r = (const float*)d_in[9];
    const float* bh   = (const float*)d_in[10];
    const float* wc   = (const float*)d_in[11];
    const float* bg   = (const float*)d_in[12];
    float* out = (float*)d_out;

    const int* src = ei;
    const int* dst = ei + NE;

    // workspace layout (16B aligned), ~34.1 MB (workspace is >=256 MB)
    char* ws = (char*)d_ws;
    int* cnt4 = (int*)(ws + 0);                               //    320,000 B (20000*4 ints)
    unsigned int* s_p = (unsigned int*)(ws + 320128);         // 12,800,000 B (20000*160*4)
    unsigned short* XH  = (unsigned short*)(ws + 13120128);   // 10,240,000 B
    unsigned short* AGG = (unsigned short*)(ws + 23360128);   // 10,240,000 B
    unsigned short* Wsz = (unsigned short*)(ws + 33600128);   //    524,288 B
    float* bias = (float*)(ws + 34124416);                    //      2,048 B

    hipMemsetAsync(cnt4, 0, NN * 4 * sizeof(int), stream);
    prep_fill_kernel<<<5120, 256, 0, stream>>>(src, dst, ew, cnt4, s_p,
                                               (const float4*)X, (const float4*)H,
                                               (unsigned int*)XH,
                                               Wx_l, Wx_r, Wh_l, Wh_r,
                                               bx, bh, bg, Wsz, bias);
    aggregate_kernel<<<NN / 4, 256, 0, stream>>>((const uint2*)XH, cnt4, s_p,
                                                 (uint2*)AGG);
    gemm_lstm_kernel<<<NTILES * 2, 256, 0, stream>>>(XH, AGG, Wsz, bias, wc, C, out);
}